// Round 5
// baseline (1395.278 us; speedup 1.0000x reference)
//
#include <hip/hip_runtime.h>
#include <hip/hip_bf16.h>

// BS=2, C=32, S=64.
// ws: [0, 96 MiB) x_cl channels-last bf16 [2][64^3][96]
//     [96 MiB, +166KB) wt2 bf16, layout [tap][ciq][oct][co][8]
// out: (2,32,64,64,64) fp32.

#define CH 32
#define CI 96

typedef __attribute__((ext_vector_type(8))) _Float16 f16x8;
typedef __attribute__((ext_vector_type(8))) short bf16x8;
typedef __attribute__((ext_vector_type(4))) float f32x4;

static __device__ __forceinline__ unsigned short f2bf(float f) {
  union { float f; unsigned u; } x; x.f = f;
  unsigned r = x.u + 0x7fff + ((x.u >> 16) & 1);   // RNE
  return (unsigned short)(r >> 16);
}

// ---------------------------------------------------------------------------
// Axial attention via f16 MFMA. One block (256 thr = 4 waves) per (b,c,s).
// Qh/Kh: [token i/j][feature m] f16.  Vt: [feature t][token j] f16.
// Wave w owns score rows i in [w*16, w*16+16).
//   QK^T: D[i][j] = sum_m Qh[i][m] Kh[j][m]  (A=Qh, B=Kh, both row-major)
//   softmax over j fully in-register (shfl_xor over the 16 r-lanes)
//   P -> LDS (reuse Qh) as [i][j] f16, then PV: O[i][t] = sum_j P[i][j] Vt[t][j]
// Writes x_cl[(b*64^3+sp)*96 + ch] directly (bf16), branch-dependent sp.
// ---------------------------------------------------------------------------
template <int BR>
__global__ __launch_bounds__(256) void attn_mfma(const float* __restrict__ q,
                                                 const float* __restrict__ k,
                                                 const float* __restrict__ v,
                                                 unsigned short* __restrict__ xcl) {
  __shared__ __align__(16) _Float16 Qh[64][72];
  __shared__ __align__(16) _Float16 Kh[64][72];
  __shared__ __align__(16) _Float16 Vt[64][72];

  const int blk0 = blockIdx.x;
  const int blk = ((blk0 & 7) << 9) | (blk0 >> 3);   // XCD chunked swizzle (4096=8*512)
  const int s = blk & 63;
  const int c = (blk >> 6) & 31;
  const int b = blk >> 11;
  const int tid = threadIdx.x;
  const size_t base = ((size_t)(b * CH + c)) << 18;

  // ---- stage Q,K (row-major) and V (transposed) as f16 ----
  #pragma unroll
  for (int ii = 0; ii < 16; ++ii) {
    const int idx = ii * 256 + tid;
    const int hi = idx >> 6, lo = idx & 63;
    int i, m;
    size_t off;
    if (BR == 0)      { m = hi; i = lo; off = (size_t)m * 4096 + (size_t)i * 64 + s; }
    else if (BR == 1) { i = hi; m = lo; off = (size_t)i * 4096 + (size_t)s * 64 + m; }
    else              { i = hi; m = lo; off = (size_t)s * 4096 + (size_t)i * 64 + m; }
    Qh[i][m] = (_Float16)q[base + off];
    Kh[i][m] = (_Float16)k[base + off];
    const int j = hi, t = lo;
    size_t offv;
    if (BR == 0)      offv = (size_t)j * 4096 + (size_t)t * 64 + s;
    else if (BR == 1) offv = (size_t)j * 4096 + (size_t)s * 64 + t;
    else              offv = (size_t)s * 4096 + (size_t)j * 64 + t;
    Vt[t][j] = (_Float16)v[base + offv];
  }
  __syncthreads();

  const int w = tid >> 6;
  const int lane = tid & 63;
  const int r = lane & 15;
  const int oct = lane >> 4;

  // ---- QK^T ----
  f32x4 sc[4];
  #pragma unroll
  for (int jt = 0; jt < 4; ++jt) sc[jt] = (f32x4){0.f, 0.f, 0.f, 0.f};
  f16x8 aq0 = *(const f16x8*)&Qh[w * 16 + r][oct * 8];
  f16x8 aq1 = *(const f16x8*)&Qh[w * 16 + r][32 + oct * 8];
  #pragma unroll
  for (int jt = 0; jt < 4; ++jt) {
    f16x8 bk0 = *(const f16x8*)&Kh[jt * 16 + r][oct * 8];
    f16x8 bk1 = *(const f16x8*)&Kh[jt * 16 + r][32 + oct * 8];
    sc[jt] = __builtin_amdgcn_mfma_f32_16x16x32_f16(aq0, bk0, sc[jt], 0, 0, 0);
    sc[jt] = __builtin_amdgcn_mfma_f32_16x16x32_f16(aq1, bk1, sc[jt], 0, 0, 0);
  }

  // ---- softmax in-register: lane holds S[i = w*16+oct*4+reg][j = jt*16+r] ----
  float P[4][4];
  #pragma unroll
  for (int reg = 0; reg < 4; ++reg) {
    float mx = fmaxf(fmaxf(sc[0][reg], sc[1][reg]), fmaxf(sc[2][reg], sc[3][reg]));
    mx = fmaxf(mx, __shfl_xor(mx, 1));
    mx = fmaxf(mx, __shfl_xor(mx, 2));
    mx = fmaxf(mx, __shfl_xor(mx, 4));
    mx = fmaxf(mx, __shfl_xor(mx, 8));
    float e[4], sum = 0.f;
    #pragma unroll
    for (int jt = 0; jt < 4; ++jt) { e[jt] = __expf(sc[jt][reg] - mx); sum += e[jt]; }
    sum += __shfl_xor(sum, 1);
    sum += __shfl_xor(sum, 2);
    sum += __shfl_xor(sum, 4);
    sum += __shfl_xor(sum, 8);
    const float inv = 1.f / sum;
    #pragma unroll
    for (int jt = 0; jt < 4; ++jt) P[reg][jt] = e[jt] * inv;
  }

  // ---- P -> LDS (reuse Qh), reorient for PV A-frags ----
  __syncthreads();   // all waves done reading Qh
  #pragma unroll
  for (int reg = 0; reg < 4; ++reg)
    #pragma unroll
    for (int jt = 0; jt < 4; ++jt)
      Qh[w * 16 + oct * 4 + reg][jt * 16 + r] = (_Float16)P[reg][jt];
  __syncthreads();

  // ---- PV ----
  f32x4 ot[4];
  #pragma unroll
  for (int tt = 0; tt < 4; ++tt) ot[tt] = (f32x4){0.f, 0.f, 0.f, 0.f};
  f16x8 ap0 = *(const f16x8*)&Qh[w * 16 + r][oct * 8];
  f16x8 ap1 = *(const f16x8*)&Qh[w * 16 + r][32 + oct * 8];
  #pragma unroll
  for (int tt = 0; tt < 4; ++tt) {
    f16x8 bv0 = *(const f16x8*)&Vt[tt * 16 + r][oct * 8];
    f16x8 bv1 = *(const f16x8*)&Vt[tt * 16 + r][32 + oct * 8];
    ot[tt] = __builtin_amdgcn_mfma_f32_16x16x32_f16(ap0, bv0, ot[tt], 0, 0, 0);
    ot[tt] = __builtin_amdgcn_mfma_f32_16x16x32_f16(ap1, bv1, ot[tt], 0, 0, 0);
  }

  // ---- store to channels-last x_cl, bf16 ----
  const int ch = BR * CH + c;
  #pragma unroll
  for (int tt = 0; tt < 4; ++tt) {
    #pragma unroll
    for (int reg = 0; reg < 4; ++reg) {
      const int i = w * 16 + oct * 4 + reg;
      const int t = tt * 16 + r;
      size_t sp;
      if (BR == 0)      sp = (size_t)i * 4096 + (size_t)t * 64 + s;
      else if (BR == 1) sp = (size_t)i * 4096 + (size_t)s * 64 + t;
      else              sp = (size_t)s * 4096 + (size_t)i * 64 + t;
      xcl[((size_t)b * 262144 + sp) * CI + ch] = f2bf(ot[tt][reg]);
    }
  }
}

// w[co][ci][dz][dy][dx] f32 -> wt2 bf16, idx = (((tap*3+ciq)*4+oct)*32 + co)*8 + e
__global__ __launch_bounds__(256) void wprep(const float* __restrict__ w,
                                             unsigned short* __restrict__ wt2) {
  int idx = blockIdx.x * 256 + threadIdx.x;
  if (idx >= 27 * 32 * 96) return;
  int tap = idx / 3072;
  int rem = idx - tap * 3072;
  int co = rem / 96, ci = rem - co * 96;
  int ciq = ci >> 5, oct = (ci >> 3) & 3, e = ci & 7;
  wt2[(((tap * 3 + ciq) * 4 + oct) * 32 + co) * 8 + e] =
      f2bf(w[((size_t)co * 96 + ci) * 27 + tap]);
}

// ---------------------------------------------------------------------------
// LDS-staged implicit-GEMM conv. Block (256 thr = 4 waves) = (b, z, 8-row y-tile).
// Per (dz, ciq) stage: XT[10 rows][66 x][36 shorts] (ci-block of 32, pad->36 so
// x-stride 72B gives conflict-free (2-way) ds_read_b128). Zero halo staged.
// Wave w owns y-rows w*2+{0,1}; acc[ry][xc][ct] over 4 x-chunks, 2 co-tiles.
// ---------------------------------------------------------------------------
__global__ __launch_bounds__(256) void conv_mfma(const unsigned short* __restrict__ xcl,
                                                 const unsigned short* __restrict__ wt2,
                                                 const float* __restrict__ cb,
                                                 const float* __restrict__ gamma,
                                                 const float* __restrict__ beta,
                                                 const float* __restrict__ mean,
                                                 const float* __restrict__ var,
                                                 float* __restrict__ out) {
  __shared__ __align__(16) unsigned short XT[23760];   // 10*66*36 shorts = 47.5 KB

  const int blk0 = blockIdx.x;                 // 1024
  const int blk = ((blk0 & 7) << 7) | (blk0 >> 3);   // XCD chunked swizzle (1024=8*128)
  const int yt = blk & 7;
  const int z = (blk >> 3) & 63;
  const int b = blk >> 9;
  const int tid = threadIdx.x;
  const int w = tid >> 6;
  const int lane = tid & 63;
  const int r = lane & 15;
  const int oct = lane >> 4;
  const int y0 = yt * 8;

  f32x4 acc[2][4][2];
  #pragma unroll
  for (int ry = 0; ry < 2; ++ry)
    #pragma unroll
    for (int xc = 0; xc < 4; ++xc)
      #pragma unroll
      for (int ct = 0; ct < 2; ++ct)
        acc[ry][xc][ct] = (f32x4){0.f, 0.f, 0.f, 0.f};

  const unsigned short* xb = xcl + (size_t)b * 262144 * CI;

  for (int dz = 0; dz < 3; ++dz) {
    const int zz = z + dz - 1;
    if ((unsigned)zz > 63u) continue;          // uniform per block
    for (int ciq = 0; ciq < 3; ++ciq) {
      __syncthreads();                         // previous stage fully consumed
      // stage 10 rows x 66 x x 4 chunks of 8ci
      #pragma unroll
      for (int ii = 0; ii < 11; ++ii) {
        const int idx = ii * 256 + tid;
        if (idx < 2640) {
          const int row = idx / 264;
          const int rem = idx - row * 264;
          const int x = rem >> 2;
          const int cq = rem & 3;
          const int gy = y0 + row - 1, gx = x - 1;
          bf16x8 val = {0, 0, 0, 0, 0, 0, 0, 0};
          if ((unsigned)gy < 64u && (unsigned)gx < 64u)
            val = *(const bf16x8*)(xb + (size_t)((zz * 64 + gy) * 64 + gx) * CI +
                                   ciq * 32 + cq * 8);
          *(bf16x8*)&XT[row * 2376 + x * 36 + cq * 8] = val;
        }
      }
      __syncthreads();

      #pragma unroll
      for (int dy = 0; dy < 3; ++dy) {
        #pragma unroll
        for (int dx = 0; dx < 3; ++dx) {
          const int tap = (dz * 3 + dy) * 3 + dx;
          const unsigned short* wp = wt2 + ((size_t)((tap * 3 + ciq) * 4 + oct)) * 256;
          bf16x8 wf0 = *(const bf16x8*)(wp + r * 8);
          bf16x8 wf1 = *(const bf16x8*)(wp + 128 + r * 8);
          #pragma unroll
          for (int ry = 0; ry < 2; ++ry) {
            const int lrow = w * 2 + ry + dy;          // 0..9
            #pragma unroll
            for (int xc = 0; xc < 4; ++xc) {
              bf16x8 af = *(const bf16x8*)&XT[lrow * 2376 + (xc * 16 + r + dx) * 36 + oct * 8];
              acc[ry][xc][0] = __builtin_amdgcn_mfma_f32_16x16x32_bf16(af, wf0, acc[ry][xc][0], 0, 0, 0);
              acc[ry][xc][1] = __builtin_amdgcn_mfma_f32_16x16x32_bf16(af, wf1, acc[ry][xc][1], 0, 0, 0);
            }
          }
        }
      }
    }
  }

  // ---- epilogue: bias + BN + ReLU, float4 stores ----
  float invc[2], shc[2], bic[2];
  #pragma unroll
  for (int ct = 0; ct < 2; ++ct) {
    const int co = ct * 16 + r;
    const float iv = gamma[co] * rsqrtf(var[co] + 1e-5f);
    invc[ct] = iv;
    shc[ct] = beta[co] - mean[co] * iv;
    bic[ct] = cb[co];
  }
  #pragma unroll
  for (int ct = 0; ct < 2; ++ct) {
    float* oc = out + (((size_t)(b * CH + ct * 16 + r)) << 18) + ((size_t)z << 12);
    #pragma unroll
    for (int ry = 0; ry < 2; ++ry) {
      const int y = y0 + w * 2 + ry;
      #pragma unroll
      for (int xc = 0; xc < 4; ++xc) {
        const f32x4 a = acc[ry][xc][ct];
        float4 st;
        st.x = fmaxf(0.f, (a[0] + bic[ct]) * invc[ct] + shc[ct]);
        st.y = fmaxf(0.f, (a[1] + bic[ct]) * invc[ct] + shc[ct]);
        st.z = fmaxf(0.f, (a[2] + bic[ct]) * invc[ct] + shc[ct]);
        st.w = fmaxf(0.f, (a[3] + bic[ct]) * invc[ct] + shc[ct]);
        *(float4*)(oc + (size_t)y * 64 + xc * 16 + oct * 4) = st;
      }
    }
  }
}

extern "C" void kernel_launch(void* const* d_in, const int* in_sizes, int n_in,
                              void* d_out, int out_size, void* d_ws, size_t ws_size,
                              hipStream_t stream) {
  const float* q     = (const float*)d_in[0];
  const float* k     = (const float*)d_in[1];
  const float* v     = (const float*)d_in[2];
  const float* cw    = (const float*)d_in[3];
  const float* cb    = (const float*)d_in[4];
  const float* gamma = (const float*)d_in[5];
  const float* beta  = (const float*)d_in[6];
  const float* mean  = (const float*)d_in[7];
  const float* var   = (const float*)d_in[8];

  unsigned short* xcl = (unsigned short*)d_ws;                            // 96 MiB
  unsigned short* wt2 = (unsigned short*)((char*)d_ws + (96ull << 20));   // 166 KB
  float* out = (float*)d_out;

  hipLaunchKernelGGL(wprep, dim3(324), dim3(256), 0, stream, cw, wt2);
  hipLaunchKernelGGL((attn_mfma<0>), dim3(4096), dim3(256), 0, stream, q, k, v, xcl);
  hipLaunchKernelGGL((attn_mfma<1>), dim3(4096), dim3(256), 0, stream, q, k, v, xcl);
  hipLaunchKernelGGL((attn_mfma<2>), dim3(4096), dim3(256), 0, stream, q, k, v, xcl);
  hipLaunchKernelGGL(conv_mfma, dim3(1024), dim3(256), 0, stream,
                     xcl, wt2, cb, gamma, beta, mean, var, out);
}

// Round 6
// 652.715 us; speedup vs baseline: 2.1377x; 2.1377x over previous
//
#include <hip/hip_runtime.h>
#include <hip/hip_bf16.h>

// BS=2, C=32, S=64.
// ws: [0, 96 MiB)        xblk  bf16  [b][ciq][64^3][32]  (blocked channels-last)
//     [96, 144 MiB)      y     bf16  [branch][c][s][4096] (per-b, reused)
//     [144 MiB, +166KB)  wt2   bf16  [tap][ciq][oct][co][8]
// out: (2,32,64,64,64) fp32.

#define CH 32

typedef __attribute__((ext_vector_type(8))) _Float16 f16x8;
typedef __attribute__((ext_vector_type(8))) short bf16x8;
typedef __attribute__((ext_vector_type(4))) float f32x4;

static __device__ __forceinline__ unsigned short f2bf(float f) {
  union { float f; unsigned u; } x; x.f = f;
  unsigned r = x.u + 0x7fff + ((x.u >> 16) & 1);   // RNE
  return (unsigned short)(r >> 16);
}

// ---------------------------------------------------------------------------
// Axial attention via f16 MFMA. One block (4 waves) per (c,s) of batch b.
// All LDS staging stores are lane-contiguous (0 conflicts). V kept row-major
// Vh[j][t] (stride 66 -> PV B-frag gather is conflict-free). Output goes
// through LDS (reuse Kh) and is written as ONE contiguous 8KB run to
// y[c][s][i*64+t].
// ---------------------------------------------------------------------------
template <int BR>
__global__ __launch_bounds__(256) void attn_mfma(const float* __restrict__ q,
                                                 const float* __restrict__ k,
                                                 const float* __restrict__ v,
                                                 unsigned short* __restrict__ ybr,
                                                 int b) {
  __shared__ __align__(16) _Float16 Qh[64][72];
  __shared__ __align__(16) _Float16 Kh[64][72];
  __shared__ __align__(16) _Float16 Vh[64][66];

  const int blk0 = blockIdx.x;
  const int blk = ((blk0 & 7) << 8) | (blk0 >> 3);   // XCD chunk (2048 = 8*256)
  const int s = blk & 63;
  const int c = blk >> 6;
  const int tid = threadIdx.x;
  const size_t base = ((size_t)(b * CH + c)) << 18;

  // ---- stage: lanes walk `lo`; every LDS store is contiguous ----
  #pragma unroll
  for (int ii = 0; ii < 16; ++ii) {
    const int idx = ii * 256 + tid;
    const int hi = idx >> 6, lo = idx & 63;
    size_t off, offv;
    if (BR == 0) {        // Q/K: hi=i, lo=m (m-walk);  V: hi=j, lo=t
      off  = (size_t)lo * 4096 + (size_t)hi * 64 + s;
      offv = (size_t)hi * 4096 + (size_t)lo * 64 + s;
    } else if (BR == 1) { // hi=i, lo=m contiguous
      off  = (size_t)hi * 4096 + (size_t)s * 64 + lo;
      offv = off;
    } else {
      off  = (size_t)s * 4096 + (size_t)hi * 64 + lo;
      offv = off;
    }
    Qh[hi][lo] = (_Float16)q[base + off];
    Kh[hi][lo] = (_Float16)k[base + off];
    Vh[hi][lo] = (_Float16)v[base + offv];
  }
  __syncthreads();

  const int w = tid >> 6;
  const int lane = tid & 63;
  const int r = lane & 15;
  const int oct = lane >> 4;

  // ---- QK^T ----
  f32x4 sc[4];
  #pragma unroll
  for (int jt = 0; jt < 4; ++jt) sc[jt] = (f32x4){0.f, 0.f, 0.f, 0.f};
  f16x8 aq0 = *(const f16x8*)&Qh[w * 16 + r][oct * 8];
  f16x8 aq1 = *(const f16x8*)&Qh[w * 16 + r][32 + oct * 8];
  #pragma unroll
  for (int jt = 0; jt < 4; ++jt) {
    f16x8 bk0 = *(const f16x8*)&Kh[jt * 16 + r][oct * 8];
    f16x8 bk1 = *(const f16x8*)&Kh[jt * 16 + r][32 + oct * 8];
    sc[jt] = __builtin_amdgcn_mfma_f32_16x16x32_f16(aq0, bk0, sc[jt], 0, 0, 0);
    sc[jt] = __builtin_amdgcn_mfma_f32_16x16x32_f16(aq1, bk1, sc[jt], 0, 0, 0);
  }

  // ---- softmax in-register: lane holds S[i=w*16+oct*4+reg][j=jt*16+r] ----
  float P[4][4];
  #pragma unroll
  for (int reg = 0; reg < 4; ++reg) {
    float mx = fmaxf(fmaxf(sc[0][reg], sc[1][reg]), fmaxf(sc[2][reg], sc[3][reg]));
    mx = fmaxf(mx, __shfl_xor(mx, 1));
    mx = fmaxf(mx, __shfl_xor(mx, 2));
    mx = fmaxf(mx, __shfl_xor(mx, 4));
    mx = fmaxf(mx, __shfl_xor(mx, 8));
    float e[4], sum = 0.f;
    #pragma unroll
    for (int jt = 0; jt < 4; ++jt) { e[jt] = __expf(sc[jt][reg] - mx); sum += e[jt]; }
    sum += __shfl_xor(sum, 1);
    sum += __shfl_xor(sum, 2);
    sum += __shfl_xor(sum, 4);
    sum += __shfl_xor(sum, 8);
    const float inv = 1.f / sum;
    #pragma unroll
    for (int jt = 0; jt < 4; ++jt) P[reg][jt] = e[jt] * inv;
  }

  // ---- P -> Qh rows [w*16, w*16+16): wave-local, no barrier needed ----
  #pragma unroll
  for (int reg = 0; reg < 4; ++reg)
    #pragma unroll
    for (int jt = 0; jt < 4; ++jt)
      Qh[w * 16 + oct * 4 + reg][jt * 16 + r] = (_Float16)P[reg][jt];

  // ---- PV: A = P rows (own wave), B = Vh columns via conflict-free gather ----
  f16x8 ap0 = *(const f16x8*)&Qh[w * 16 + r][oct * 8];
  f16x8 ap1 = *(const f16x8*)&Qh[w * 16 + r][32 + oct * 8];
  f32x4 ot[4];
  #pragma unroll
  for (int tt = 0; tt < 4; ++tt) {
    ot[tt] = (f32x4){0.f, 0.f, 0.f, 0.f};
    f16x8 bv0, bv1;
    #pragma unroll
    for (int e = 0; e < 8; ++e) {
      bv0[e] = Vh[oct * 8 + e][tt * 16 + r];
      bv1[e] = Vh[32 + oct * 8 + e][tt * 16 + r];
    }
    ot[tt] = __builtin_amdgcn_mfma_f32_16x16x32_f16(ap0, bv0, ot[tt], 0, 0, 0);
    ot[tt] = __builtin_amdgcn_mfma_f32_16x16x32_f16(ap1, bv1, ot[tt], 0, 0, 0);
  }

  // ---- O -> LDS (reuse Kh as bf16) -> one contiguous 8KB global write ----
  __syncthreads();                       // everyone done reading Kh B-frags
  unsigned short* Ot = (unsigned short*)&Kh[0][0];   // stride 72
  #pragma unroll
  for (int tt = 0; tt < 4; ++tt)
    #pragma unroll
    for (int reg = 0; reg < 4; ++reg)
      Ot[(size_t)(w * 16 + oct * 4 + reg) * 72 + tt * 16 + r] = f2bf(ot[tt][reg]);
  __syncthreads();

  {
    const int i = tid >> 2, seg = tid & 3;
    const unsigned short* src = Ot + (size_t)i * 72 + seg * 16;
    bf16x8 a0 = *(const bf16x8*)(src);
    bf16x8 a1 = *(const bf16x8*)(src + 8);
    unsigned short* dst = ybr + ((size_t)(c * 64 + s)) * 4096 + tid * 16;
    *(bf16x8*)(dst) = a0;
    *(bf16x8*)(dst + 8) = a1;
  }
}

// ---------------------------------------------------------------------------
// repack<BR>: y[c][s][i*64+t] -> xblk[(b*3+BR)][sp][32c], all coalesced.
// Spatial map per branch: BR0 (z,y,x)=(i,t,s); BR1 (i,s,t); BR2 (s,i,t).
// Block = (z, oct) where oct = y-oct (BR1/2) or x-oct (BR0). 512 sp x 32 c.
// LDS Ls[c*530 + o]: 265 = 9 mod 32 (coprime) -> all phases conflict-free.
// ---------------------------------------------------------------------------
template <int BR>
__global__ __launch_bounds__(256) void repack(const unsigned short* __restrict__ ybr,
                                              unsigned short* __restrict__ xblk,
                                              int b) {
  __shared__ unsigned short Ls[32 * 530];
  const int blk = blockIdx.x;        // 512
  const int oc = blk & 7;
  const int z = blk >> 3;
  const int tid = threadIdx.x;
  const int c = tid & 31;
  const int w8 = tid >> 5;           // 0..7

  // one contiguous 64-element source run per thread
  size_t src;
  if (BR == 2) src = ((size_t)(c * 64 + z)) * 4096 + (size_t)(oc * 8 + w8) * 64;
  else         src = ((size_t)(c * 64 + oc * 8 + w8)) * 4096 + (size_t)z * 64;

  #pragma unroll
  for (int kk = 0; kk < 8; ++kk) {
    bf16x8 vv = *(const bf16x8*)(ybr + src + kk * 8);
    #pragma unroll
    for (int e = 0; e < 8; ++e) {
      const int l = kk * 8 + e;
      const int li = (BR == 0) ? (l * 8 + w8) : (w8 * 64 + l);
      Ls[c * 530 + li] = (unsigned short)vv[e];
    }
  }
  __syncthreads();

  unsigned short* xq = xblk + ((size_t)(b * 3 + BR)) * 262144 * 32;
  #pragma unroll
  for (int p = 0; p < 2; ++p) {
    const int o = p * 256 + tid;
    bf16x8 o0, o1, o2, o3;
    #pragma unroll
    for (int e = 0; e < 8; ++e) {
      o0[e] = (short)Ls[(e)      * 530 + o];
      o1[e] = (short)Ls[(8 + e)  * 530 + o];
      o2[e] = (short)Ls[(16 + e) * 530 + o];
      o3[e] = (short)Ls[(24 + e) * 530 + o];
    }
    int sp;
    if (BR == 0) sp = z * 4096 + (o >> 3) * 64 + oc * 8 + (o & 7);
    else         sp = z * 4096 + oc * 512 + o;
    unsigned short* dst = xq + (size_t)sp * 32;
    *(bf16x8*)(dst)      = o0;
    *(bf16x8*)(dst + 8)  = o1;
    *(bf16x8*)(dst + 16) = o2;
    *(bf16x8*)(dst + 24) = o3;
  }
}

// w[co][ci][dz][dy][dx] f32 -> wt2 bf16, idx = (((tap*3+ciq)*4+oct)*32 + co)*8 + e
__global__ __launch_bounds__(256) void wprep(const float* __restrict__ w,
                                             unsigned short* __restrict__ wt2) {
  int idx = blockIdx.x * 256 + threadIdx.x;
  if (idx >= 27 * 32 * 96) return;
  int tap = idx / 3072;
  int rem = idx - tap * 3072;
  int co = rem / 96, ci = rem - co * 96;
  int ciq = ci >> 5, oct = (ci >> 3) & 3, e = ci & 7;
  wt2[(((tap * 3 + ciq) * 4 + oct) * 32 + co) * 8 + e] =
      f2bf(w[((size_t)co * 96 + ci) * 27 + tap]);
}

// ---------------------------------------------------------------------------
// LDS-staged implicit-GEMM conv (blocked channels-last input).
// Block (4 waves) = (b, z, 8-row y-tile); per (dz,ciq) stage XT[10][66][36].
// ---------------------------------------------------------------------------
__global__ __launch_bounds__(256) void conv_mfma(const unsigned short* __restrict__ xblk,
                                                 const unsigned short* __restrict__ wt2,
                                                 const float* __restrict__ cb,
                                                 const float* __restrict__ gamma,
                                                 const float* __restrict__ beta,
                                                 const float* __restrict__ mean,
                                                 const float* __restrict__ var,
                                                 float* __restrict__ out) {
  __shared__ __align__(16) unsigned short XT[23760];   // 10*66*36 shorts

  const int blk0 = blockIdx.x;                       // 1024
  const int blk = ((blk0 & 7) << 7) | (blk0 >> 3);   // XCD chunk (1024 = 8*128)
  const int yt = blk & 7;
  const int z = (blk >> 3) & 63;
  const int b = blk >> 9;
  const int tid = threadIdx.x;
  const int w = tid >> 6;
  const int lane = tid & 63;
  const int r = lane & 15;
  const int oct = lane >> 4;
  const int y0 = yt * 8;

  f32x4 acc[2][4][2];
  #pragma unroll
  for (int ry = 0; ry < 2; ++ry)
    #pragma unroll
    for (int xc = 0; xc < 4; ++xc)
      #pragma unroll
      for (int ct = 0; ct < 2; ++ct)
        acc[ry][xc][ct] = (f32x4){0.f, 0.f, 0.f, 0.f};

  for (int dz = 0; dz < 3; ++dz) {
    const int zz = z + dz - 1;
    if ((unsigned)zz > 63u) continue;
    for (int ciq = 0; ciq < 3; ++ciq) {
      const unsigned short* xq = xblk + ((size_t)(b * 3 + ciq)) * 262144 * 32;
      __syncthreads();
      #pragma unroll
      for (int ii = 0; ii < 11; ++ii) {
        const int idx = ii * 256 + tid;
        if (idx < 2640) {
          const int row = idx / 264;
          const int rem = idx - row * 264;
          const int x = rem >> 2;
          const int cq = rem & 3;
          const int gy = y0 + row - 1, gx = x - 1;
          bf16x8 val = {0, 0, 0, 0, 0, 0, 0, 0};
          if ((unsigned)gy < 64u && (unsigned)gx < 64u)
            val = *(const bf16x8*)(xq + (size_t)((zz * 64 + gy) * 64 + gx) * 32 + cq * 8);
          *(bf16x8*)&XT[row * 2376 + x * 36 + cq * 8] = val;
        }
      }
      __syncthreads();

      #pragma unroll
      for (int dy = 0; dy < 3; ++dy) {
        #pragma unroll
        for (int dx = 0; dx < 3; ++dx) {
          const int tap = (dz * 3 + dy) * 3 + dx;
          const unsigned short* wp = wt2 + ((size_t)((tap * 3 + ciq) * 4 + oct)) * 256;
          bf16x8 wf0 = *(const bf16x8*)(wp + r * 8);
          bf16x8 wf1 = *(const bf16x8*)(wp + 128 + r * 8);
          #pragma unroll
          for (int ry = 0; ry < 2; ++ry) {
            const int lrow = w * 2 + ry + dy;          // 0..9
            #pragma unroll
            for (int xc = 0; xc < 4; ++xc) {
              bf16x8 af = *(const bf16x8*)&XT[lrow * 2376 + (xc * 16 + r + dx) * 36 + oct * 8];
              acc[ry][xc][0] = __builtin_amdgcn_mfma_f32_16x16x32_bf16(af, wf0, acc[ry][xc][0], 0, 0, 0);
              acc[ry][xc][1] = __builtin_amdgcn_mfma_f32_16x16x32_bf16(af, wf1, acc[ry][xc][1], 0, 0, 0);
            }
          }
        }
      }
    }
  }

  float invc[2], shc[2], bic[2];
  #pragma unroll
  for (int ct = 0; ct < 2; ++ct) {
    const int co = ct * 16 + r;
    const float iv = gamma[co] * rsqrtf(var[co] + 1e-5f);
    invc[ct] = iv;
    shc[ct] = beta[co] - mean[co] * iv;
    bic[ct] = cb[co];
  }
  #pragma unroll
  for (int ct = 0; ct < 2; ++ct) {
    float* oc = out + (((size_t)(b * CH + ct * 16 + r)) << 18) + ((size_t)z << 12);
    #pragma unroll
    for (int ry = 0; ry < 2; ++ry) {
      const int y = y0 + w * 2 + ry;
      #pragma unroll
      for (int xc = 0; xc < 4; ++xc) {
        const f32x4 a = acc[ry][xc][ct];
        float4 st;
        st.x = fmaxf(0.f, (a[0] + bic[ct]) * invc[ct] + shc[ct]);
        st.y = fmaxf(0.f, (a[1] + bic[ct]) * invc[ct] + shc[ct]);
        st.z = fmaxf(0.f, (a[2] + bic[ct]) * invc[ct] + shc[ct]);
        st.w = fmaxf(0.f, (a[3] + bic[ct]) * invc[ct] + shc[ct]);
        *(float4*)(oc + (size_t)y * 64 + xc * 16 + oct * 4) = st;
      }
    }
  }
}

extern "C" void kernel_launch(void* const* d_in, const int* in_sizes, int n_in,
                              void* d_out, int out_size, void* d_ws, size_t ws_size,
                              hipStream_t stream) {
  const float* q     = (const float*)d_in[0];
  const float* k     = (const float*)d_in[1];
  const float* v     = (const float*)d_in[2];
  const float* cw    = (const float*)d_in[3];
  const float* cb    = (const float*)d_in[4];
  const float* gamma = (const float*)d_in[5];
  const float* beta  = (const float*)d_in[6];
  const float* mean  = (const float*)d_in[7];
  const float* var   = (const float*)d_in[8];

  unsigned short* xblk = (unsigned short*)d_ws;                             // 96 MiB
  unsigned short* ybuf = (unsigned short*)((char*)d_ws + (96ull << 20));    // 48 MiB
  unsigned short* wt2  = (unsigned short*)((char*)d_ws + (144ull << 20));   // 166 KB
  unsigned short* y0 = ybuf;
  unsigned short* y1 = ybuf + 8388608;
  unsigned short* y2 = ybuf + 16777216;
  float* out = (float*)d_out;

  hipLaunchKernelGGL(wprep, dim3(324), dim3(256), 0, stream, cw, wt2);
  for (int b = 0; b < 2; ++b) {
    hipLaunchKernelGGL((attn_mfma<0>), dim3(2048), dim3(256), 0, stream, q, k, v, y0, b);
    hipLaunchKernelGGL((attn_mfma<1>), dim3(2048), dim3(256), 0, stream, q, k, v, y1, b);
    hipLaunchKernelGGL((attn_mfma<2>), dim3(2048), dim3(256), 0, stream, q, k, v, y2, b);
    hipLaunchKernelGGL((repack<0>), dim3(512), dim3(256), 0, stream, y0, xblk, b);
    hipLaunchKernelGGL((repack<1>), dim3(512), dim3(256), 0, stream, y1, xblk, b);
    hipLaunchKernelGGL((repack<2>), dim3(512), dim3(256), 0, stream, y2, xblk, b);
  }
  hipLaunchKernelGGL(conv_mfma, dim3(1024), dim3(256), 0, stream,
                     xblk, wt2, cb, gamma, beta, mean, var, out);
}

// Round 7
// 488.442 us; speedup vs baseline: 2.8566x; 1.3363x over previous
//
#include <hip/hip_runtime.h>
#include <hip/hip_bf16.h>

// BS=2, C=32, S=64.
// ws: [0, 96 MiB)        xblk bf16 [b][ciq][64^3][32]   (blocked channels-last)
//     [96, 112 MiB)      y    bf16 [c][s][4096]          (single buffer, reused per branch)
//     [112,128,144 MiB)  qT,kT,vT f16 [c][d][w][h]       (per-b, reused)
//     [160 MiB, +166KB)  wt2  bf16 [tap][ciq][oct][co][8]
// out: (2,32,64,64,64) fp32.

#define CH 32

typedef __attribute__((ext_vector_type(8))) _Float16 f16x8;
typedef __attribute__((ext_vector_type(4))) _Float16 f16x4;
typedef __attribute__((ext_vector_type(8))) short bf16x8;
typedef __attribute__((ext_vector_type(4))) float f32x4;

static __device__ __forceinline__ unsigned short f2bf(float f) {
  union { float f; unsigned u; } x; x.f = f;
  unsigned r = x.u + 0x7fff + ((x.u >> 16) & 1);   // RNE
  return (unsigned short)(r >> 16);
}

// ---------------------------------------------------------------------------
// trans_dwh: q/k/v f32 [c][h][w][d] -> f16 [c][d][w][h] (one batch b).
// Block per (c, w): plane (h,d). Reads 16B/lane in 64B segments; writes
// 16B/lane in 128B runs per d. LDS Ls[d*72+h].
// ---------------------------------------------------------------------------
__global__ __launch_bounds__(256) void trans_dwh(const float* __restrict__ q,
                                                 const float* __restrict__ k,
                                                 const float* __restrict__ v,
                                                 _Float16* __restrict__ qT,
                                                 _Float16* __restrict__ kT,
                                                 _Float16* __restrict__ vT,
                                                 int b) {
  __shared__ __align__(16) _Float16 Ls[64 * 72];
  const int blk = blockIdx.x;          // 2048 = c*64 + w
  const int c = blk >> 6;
  const int w = blk & 63;
  const int tid = threadIdx.x;
  const size_t bc = (size_t)(b * CH + c);
  const float* srcs[3] = {q, k, v};
  _Float16* dsts[3] = {qT, kT, vT};
  const int h = tid >> 2, dq = tid & 3;

  for (int tz = 0; tz < 3; ++tz) {
    const float* sp = srcs[tz] + bc * 262144 + (size_t)h * 4096 + (size_t)w * 64;
    #pragma unroll
    for (int pp = 0; pp < 4; ++pp) {
      const int d0 = dq * 16 + pp * 4;
      const float4 ld = *(const float4*)(sp + d0);
      Ls[(d0 + 0) * 72 + h] = (_Float16)ld.x;
      Ls[(d0 + 1) * 72 + h] = (_Float16)ld.y;
      Ls[(d0 + 2) * 72 + h] = (_Float16)ld.z;
      Ls[(d0 + 3) * 72 + h] = (_Float16)ld.w;
    }
    __syncthreads();
    _Float16* dp = dsts[tz] + (size_t)c * 262144 + (size_t)w * 64;
    #pragma unroll
    for (int p = 0; p < 2; ++p) {
      const int idx = p * 256 + tid;
      const int d = idx >> 3, o = (idx & 7) * 8;
      *(f16x8*)(dp + (size_t)d * 4096 + o) = *(const f16x8*)&Ls[d * 72 + o];
    }
    __syncthreads();
  }
}

// ---------------------------------------------------------------------------
// Axial attention via f16 MFMA. One block (4 waves) per (c,s) of batch b.
// BR0 reads pre-transposed qT/kT/vT planes [w][h] (fully coalesced 16B loads);
// BR1/2 read originals with float4 loads. V staged row-major: BR0 as
// Vt[t][j] (vector B-frag reads), BR1/2 as Vh[j][t] (scalar gather).
// Output through LDS -> one contiguous 8KB store to y[c][s][4096].
// ---------------------------------------------------------------------------
template <int BR>
__global__ __launch_bounds__(256) void attn_mfma(const float* __restrict__ q,
                                                 const float* __restrict__ k,
                                                 const float* __restrict__ v,
                                                 const _Float16* __restrict__ qT,
                                                 const _Float16* __restrict__ kT,
                                                 const _Float16* __restrict__ vT,
                                                 unsigned short* __restrict__ ybr,
                                                 int b) {
  __shared__ __align__(16) _Float16 Qh[64][72];
  __shared__ __align__(16) _Float16 Kh[64][72];
  __shared__ __align__(16) _Float16 Vh[64][72];

  const int blk0 = blockIdx.x;
  const int blk = ((blk0 & 7) << 8) | (blk0 >> 3);   // XCD chunk (2048 = 8*256)
  const int s = blk & 63;
  const int c = blk >> 6;
  const int tid = threadIdx.x;

  if (BR == 0) {
    const _Float16* qp = qT + ((size_t)c * 64 + s) * 4096;
    const _Float16* kp = kT + ((size_t)c * 64 + s) * 4096;
    const _Float16* vp = vT + ((size_t)c * 64 + s) * 4096;
    #pragma unroll
    for (int ii = 0; ii < 2; ++ii) {
      const int idx = ii * 256 + tid;
      const int row = idx >> 3, ch = (idx & 7) * 8;
      *(f16x8*)&Qh[row][ch] = *(const f16x8*)(qp + row * 64 + ch);
      *(f16x8*)&Kh[row][ch] = *(const f16x8*)(kp + row * 64 + ch);
      *(f16x8*)&Vh[row][ch] = *(const f16x8*)(vp + row * 64 + ch);   // Vt[t][j]
    }
  } else {
    const size_t base = ((size_t)(b * CH + c)) << 18;
    #pragma unroll
    for (int ii = 0; ii < 4; ++ii) {
      const int idx = ii * 256 + tid;
      const int hi = idx >> 4, lo = (idx & 15) * 4;
      size_t off;
      if (BR == 1) off = (size_t)hi * 4096 + (size_t)s * 64 + lo;
      else         off = (size_t)s * 4096 + (size_t)hi * 64 + lo;
      const float4 lq = *(const float4*)(q + base + off);
      const float4 lk = *(const float4*)(k + base + off);
      const float4 lv = *(const float4*)(v + base + off);
      *(f16x4*)&Qh[hi][lo] = (f16x4){(_Float16)lq.x, (_Float16)lq.y, (_Float16)lq.z, (_Float16)lq.w};
      *(f16x4*)&Kh[hi][lo] = (f16x4){(_Float16)lk.x, (_Float16)lk.y, (_Float16)lk.z, (_Float16)lk.w};
      *(f16x4*)&Vh[hi][lo] = (f16x4){(_Float16)lv.x, (_Float16)lv.y, (_Float16)lv.z, (_Float16)lv.w};
    }
  }
  __syncthreads();

  const int w = tid >> 6;
  const int lane = tid & 63;
  const int r = lane & 15;
  const int oct = lane >> 4;

  // ---- QK^T ----
  f32x4 sc[4];
  #pragma unroll
  for (int jt = 0; jt < 4; ++jt) sc[jt] = (f32x4){0.f, 0.f, 0.f, 0.f};
  f16x8 aq0 = *(const f16x8*)&Qh[w * 16 + r][oct * 8];
  f16x8 aq1 = *(const f16x8*)&Qh[w * 16 + r][32 + oct * 8];
  #pragma unroll
  for (int jt = 0; jt < 4; ++jt) {
    f16x8 bk0 = *(const f16x8*)&Kh[jt * 16 + r][oct * 8];
    f16x8 bk1 = *(const f16x8*)&Kh[jt * 16 + r][32 + oct * 8];
    sc[jt] = __builtin_amdgcn_mfma_f32_16x16x32_f16(aq0, bk0, sc[jt], 0, 0, 0);
    sc[jt] = __builtin_amdgcn_mfma_f32_16x16x32_f16(aq1, bk1, sc[jt], 0, 0, 0);
  }

  // ---- softmax in-register: lane holds S[i=w*16+oct*4+reg][j=jt*16+r] ----
  float P[4][4];
  #pragma unroll
  for (int reg = 0; reg < 4; ++reg) {
    float mx = fmaxf(fmaxf(sc[0][reg], sc[1][reg]), fmaxf(sc[2][reg], sc[3][reg]));
    mx = fmaxf(mx, __shfl_xor(mx, 1));
    mx = fmaxf(mx, __shfl_xor(mx, 2));
    mx = fmaxf(mx, __shfl_xor(mx, 4));
    mx = fmaxf(mx, __shfl_xor(mx, 8));
    float e[4], sum = 0.f;
    #pragma unroll
    for (int jt = 0; jt < 4; ++jt) { e[jt] = __expf(sc[jt][reg] - mx); sum += e[jt]; }
    sum += __shfl_xor(sum, 1);
    sum += __shfl_xor(sum, 2);
    sum += __shfl_xor(sum, 4);
    sum += __shfl_xor(sum, 8);
    const float inv = 1.f / sum;
    #pragma unroll
    for (int jt = 0; jt < 4; ++jt) P[reg][jt] = e[jt] * inv;
  }

  // ---- P -> Qh rows [w*16, w*16+16): wave-local, no barrier needed ----
  #pragma unroll
  for (int reg = 0; reg < 4; ++reg)
    #pragma unroll
    for (int jt = 0; jt < 4; ++jt)
      Qh[w * 16 + oct * 4 + reg][jt * 16 + r] = (_Float16)P[reg][jt];

  // ---- PV ----
  f16x8 ap0 = *(const f16x8*)&Qh[w * 16 + r][oct * 8];
  f16x8 ap1 = *(const f16x8*)&Qh[w * 16 + r][32 + oct * 8];
  f32x4 ot[4];
  #pragma unroll
  for (int tt = 0; tt < 4; ++tt) {
    ot[tt] = (f32x4){0.f, 0.f, 0.f, 0.f};
    f16x8 bv0, bv1;
    if (BR == 0) {   // Vh holds Vt[t][j]: contiguous b128 row reads
      bv0 = *(const f16x8*)&Vh[tt * 16 + r][oct * 8];
      bv1 = *(const f16x8*)&Vh[tt * 16 + r][32 + oct * 8];
    } else {         // Vh[j][t]: scalar gather
      #pragma unroll
      for (int e = 0; e < 8; ++e) {
        bv0[e] = Vh[oct * 8 + e][tt * 16 + r];
        bv1[e] = Vh[32 + oct * 8 + e][tt * 16 + r];
      }
    }
    ot[tt] = __builtin_amdgcn_mfma_f32_16x16x32_f16(ap0, bv0, ot[tt], 0, 0, 0);
    ot[tt] = __builtin_amdgcn_mfma_f32_16x16x32_f16(ap1, bv1, ot[tt], 0, 0, 0);
  }

  // ---- O -> LDS (reuse Kh as bf16) -> one contiguous 8KB global write ----
  __syncthreads();
  unsigned short* Ot = (unsigned short*)&Kh[0][0];   // stride 72
  #pragma unroll
  for (int tt = 0; tt < 4; ++tt)
    #pragma unroll
    for (int reg = 0; reg < 4; ++reg)
      Ot[(size_t)(w * 16 + oct * 4 + reg) * 72 + tt * 16 + r] = f2bf(ot[tt][reg]);
  __syncthreads();

  {
    const int i = tid >> 2, seg = tid & 3;
    const unsigned short* src = Ot + (size_t)i * 72 + seg * 16;
    bf16x8 a0 = *(const bf16x8*)(src);
    bf16x8 a1 = *(const bf16x8*)(src + 8);
    unsigned short* dst = ybr + ((size_t)(c * 64 + s)) * 4096 + tid * 16;
    *(bf16x8*)(dst) = a0;
    *(bf16x8*)(dst + 8) = a1;
  }
}

// ---------------------------------------------------------------------------
// repack<BR>: y[c][s][i*64+t] -> xblk[(b*3+BR)][sp][32c], all coalesced.
// ---------------------------------------------------------------------------
template <int BR>
__global__ __launch_bounds__(256) void repack(const unsigned short* __restrict__ ybr,
                                              unsigned short* __restrict__ xblk,
                                              int b) {
  __shared__ unsigned short Ls[32 * 530];
  const int blk = blockIdx.x;        // 512
  const int oc = blk & 7;
  const int z = blk >> 3;
  const int tid = threadIdx.x;
  const int c = tid & 31;
  const int w8 = tid >> 5;           // 0..7

  size_t src;
  if (BR == 2) src = ((size_t)(c * 64 + z)) * 4096 + (size_t)(oc * 8 + w8) * 64;
  else         src = ((size_t)(c * 64 + oc * 8 + w8)) * 4096 + (size_t)z * 64;

  #pragma unroll
  for (int kk = 0; kk < 8; ++kk) {
    bf16x8 vv = *(const bf16x8*)(ybr + src + kk * 8);
    #pragma unroll
    for (int e = 0; e < 8; ++e) {
      const int l = kk * 8 + e;
      const int li = (BR == 0) ? (l * 8 + w8) : (w8 * 64 + l);
      Ls[c * 530 + li] = (unsigned short)vv[e];
    }
  }
  __syncthreads();

  unsigned short* xq = xblk + ((size_t)(b * 3 + BR)) * 262144 * 32;
  #pragma unroll
  for (int p = 0; p < 2; ++p) {
    const int o = p * 256 + tid;
    bf16x8 o0, o1, o2, o3;
    #pragma unroll
    for (int e = 0; e < 8; ++e) {
      o0[e] = (short)Ls[(e)      * 530 + o];
      o1[e] = (short)Ls[(8 + e)  * 530 + o];
      o2[e] = (short)Ls[(16 + e) * 530 + o];
      o3[e] = (short)Ls[(24 + e) * 530 + o];
    }
    int sp;
    if (BR == 0) sp = z * 4096 + (o >> 3) * 64 + oc * 8 + (o & 7);
    else         sp = z * 4096 + oc * 512 + o;
    unsigned short* dst = xq + (size_t)sp * 32;
    *(bf16x8*)(dst)      = o0;
    *(bf16x8*)(dst + 8)  = o1;
    *(bf16x8*)(dst + 16) = o2;
    *(bf16x8*)(dst + 24) = o3;
  }
}

// w[co][ci][dz][dy][dx] f32 -> wt2 bf16, idx = (((tap*3+ciq)*4+oct)*32 + co)*8 + e
__global__ __launch_bounds__(256) void wprep(const float* __restrict__ w,
                                             unsigned short* __restrict__ wt2) {
  int idx = blockIdx.x * 256 + threadIdx.x;
  if (idx >= 27 * 32 * 96) return;
  int tap = idx / 3072;
  int rem = idx - tap * 3072;
  int co = rem / 96, ci = rem - co * 96;
  int ciq = ci >> 5, oct = (ci >> 3) & 3, e = ci & 7;
  wt2[(((tap * 3 + ciq) * 4 + oct) * 32 + co) * 8 + e] =
      f2bf(w[((size_t)co * 96 + ci) * 27 + tap]);
}

// ---------------------------------------------------------------------------
// Double-buffered LDS-staged implicit-GEMM conv.
// Block (4 waves) = (b, z, 8-row y-tile, x-half). Per (dz,ciq) stage:
// XT[buf][10 rows][34 x][36 shorts] (24 KB). Pipeline: issue next-stage global
// loads into regs, compute current buf, barrier, write regs->other buf.
// ---------------------------------------------------------------------------
__global__ __launch_bounds__(256) void conv_mfma(const unsigned short* __restrict__ xblk,
                                                 const unsigned short* __restrict__ wt2,
                                                 const float* __restrict__ cb,
                                                 const float* __restrict__ gamma,
                                                 const float* __restrict__ beta,
                                                 const float* __restrict__ mean,
                                                 const float* __restrict__ var,
                                                 float* __restrict__ out) {
  __shared__ __align__(16) unsigned short XT[2][12240];   // 2 x 10*34*36

  const int blk0 = blockIdx.x;                       // 2048
  const int blk = ((blk0 & 7) << 8) | (blk0 >> 3);   // XCD chunk (2048 = 8*256)
  const int xh = blk & 1;
  const int yt = (blk >> 1) & 7;
  const int z = (blk >> 4) & 63;
  const int b = blk >> 10;
  const int tid = threadIdx.x;
  const int w = tid >> 6;
  const int lane = tid & 63;
  const int r = lane & 15;
  const int oct = lane >> 4;
  const int y0 = yt * 8;
  const int x0 = xh * 32;

  f32x4 acc[2][2][2];
  #pragma unroll
  for (int ry = 0; ry < 2; ++ry)
    #pragma unroll
    for (int xc = 0; xc < 2; ++xc)
      #pragma unroll
      for (int ct = 0; ct < 2; ++ct)
        acc[ry][xc][ct] = (f32x4){0.f, 0.f, 0.f, 0.f};

  int stg[9], ns = 0;
  #pragma unroll
  for (int dz = 0; dz < 3; ++dz) {
    if ((unsigned)(z + dz - 1) > 63u) continue;
    for (int ciq = 0; ciq < 3; ++ciq) stg[ns++] = dz * 3 + ciq;
  }

  bf16x8 rv[6];

  auto LOAD = [&](int s) {
    const int dz = s / 3, ciq = s - dz * 3;
    const int zz = z + dz - 1;
    const unsigned short* xq = xblk + ((size_t)(b * 3 + ciq)) * (262144ull * 32) +
                               (size_t)zz * (4096 * 32);
    #pragma unroll
    for (int ii = 0; ii < 6; ++ii) {
      const int idx = ii * 256 + tid;
      bf16x8 val = {0, 0, 0, 0, 0, 0, 0, 0};
      if (idx < 1360) {
        const int row = idx / 136;
        const int rem = idx - row * 136;
        const int x = rem >> 2, cq = rem & 3;
        const int gy = y0 + row - 1, gx = x0 + x - 1;
        if ((unsigned)gy < 64u && (unsigned)gx < 64u)
          val = *(const bf16x8*)(xq + (size_t)(gy * 64 + gx) * 32 + cq * 8);
      }
      rv[ii] = val;
    }
  };
  auto WRITE = [&](unsigned short* buf) {
    #pragma unroll
    for (int ii = 0; ii < 6; ++ii) {
      const int idx = ii * 256 + tid;
      if (idx < 1360) {
        const int row = idx / 136;
        const int rem = idx - row * 136;
        const int x = rem >> 2, cq = rem & 3;
        *(bf16x8*)&buf[row * 1224 + x * 36 + cq * 8] = rv[ii];
      }
    }
  };
  auto COMPUTE = [&](const unsigned short* buf, int s) {
    const int dz = s / 3, ciq = s - dz * 3;
    #pragma unroll
    for (int dy = 0; dy < 3; ++dy) {
      #pragma unroll
      for (int dx = 0; dx < 3; ++dx) {
        const int tap = (dz * 3 + dy) * 3 + dx;
        const unsigned short* wp = wt2 + ((size_t)((tap * 3 + ciq) * 4 + oct)) * 256;
        bf16x8 wf0 = *(const bf16x8*)(wp + r * 8);
        bf16x8 wf1 = *(const bf16x8*)(wp + 128 + r * 8);
        #pragma unroll
        for (int ry = 0; ry < 2; ++ry) {
          const int lrow = w * 2 + ry + dy;          // 0..9
          #pragma unroll
          for (int xc = 0; xc < 2; ++xc) {
            bf16x8 af = *(const bf16x8*)&buf[lrow * 1224 + (xc * 16 + r + dx) * 36 + oct * 8];
            acc[ry][xc][0] = __builtin_amdgcn_mfma_f32_16x16x32_bf16(af, wf0, acc[ry][xc][0], 0, 0, 0);
            acc[ry][xc][1] = __builtin_amdgcn_mfma_f32_16x16x32_bf16(af, wf1, acc[ry][xc][1], 0, 0, 0);
          }
        }
      }
    }
  };

  LOAD(stg[0]);
  WRITE(&XT[0][0]);
  __syncthreads();
  for (int t = 0; t < ns; ++t) {
    if (t + 1 < ns) LOAD(stg[t + 1]);
    COMPUTE(&XT[t & 1][0], stg[t]);
    __syncthreads();
    if (t + 1 < ns) WRITE(&XT[(t + 1) & 1][0]);
    __syncthreads();
  }

  float invc[2], shc[2], bic[2];
  #pragma unroll
  for (int ct = 0; ct < 2; ++ct) {
    const int co = ct * 16 + r;
    const float iv = gamma[co] * rsqrtf(var[co] + 1e-5f);
    invc[ct] = iv;
    shc[ct] = beta[co] - mean[co] * iv;
    bic[ct] = cb[co];
  }
  #pragma unroll
  for (int ct = 0; ct < 2; ++ct) {
    float* oc = out + (((size_t)(b * CH + ct * 16 + r)) << 18) + ((size_t)z << 12);
    #pragma unroll
    for (int ry = 0; ry < 2; ++ry) {
      const int y = y0 + w * 2 + ry;
      #pragma unroll
      for (int xc = 0; xc < 2; ++xc) {
        const f32x4 a = acc[ry][xc][ct];
        float4 st;
        st.x = fmaxf(0.f, (a[0] + bic[ct]) * invc[ct] + shc[ct]);
        st.y = fmaxf(0.f, (a[1] + bic[ct]) * invc[ct] + shc[ct]);
        st.z = fmaxf(0.f, (a[2] + bic[ct]) * invc[ct] + shc[ct]);
        st.w = fmaxf(0.f, (a[3] + bic[ct]) * invc[ct] + shc[ct]);
        *(float4*)(oc + (size_t)y * 64 + x0 + xc * 16 + oct * 4) = st;
      }
    }
  }
}

extern "C" void kernel_launch(void* const* d_in, const int* in_sizes, int n_in,
                              void* d_out, int out_size, void* d_ws, size_t ws_size,
                              hipStream_t stream) {
  const float* q     = (const float*)d_in[0];
  const float* k     = (const float*)d_in[1];
  const float* v     = (const float*)d_in[2];
  const float* cw    = (const float*)d_in[3];
  const float* cb    = (const float*)d_in[4];
  const float* gamma = (const float*)d_in[5];
  const float* beta  = (const float*)d_in[6];
  const float* mean  = (const float*)d_in[7];
  const float* var   = (const float*)d_in[8];

  unsigned short* xblk = (unsigned short*)d_ws;                             // 96 MiB
  unsigned short* ybuf = (unsigned short*)((char*)d_ws + (96ull  << 20));   // 16 MiB
  _Float16*       qT   = (_Float16*)((char*)d_ws + (112ull << 20));         // 16 MiB
  _Float16*       kT   = (_Float16*)((char*)d_ws + (128ull << 20));         // 16 MiB
  _Float16*       vT   = (_Float16*)((char*)d_ws + (144ull << 20));         // 16 MiB
  unsigned short* wt2  = (unsigned short*)((char*)d_ws + (160ull << 20));   // 166 KB
  float* out = (float*)d_out;

  hipLaunchKernelGGL(wprep, dim3(324), dim3(256), 0, stream, cw, wt2);
  for (int b = 0; b < 2; ++b) {
    hipLaunchKernelGGL(trans_dwh, dim3(2048), dim3(256), 0, stream, q, k, v, qT, kT, vT, b);
    hipLaunchKernelGGL((attn_mfma<0>), dim3(2048), dim3(256), 0, stream, q, k, v, qT, kT, vT, ybuf, b);
    hipLaunchKernelGGL((repack<0>), dim3(512), dim3(256), 0, stream, ybuf, xblk, b);
    hipLaunchKernelGGL((attn_mfma<1>), dim3(2048), dim3(256), 0, stream, q, k, v, qT, kT, vT, ybuf, b);
    hipLaunchKernelGGL((repack<1>), dim3(512), dim3(256), 0, stream, ybuf, xblk, b);
    hipLaunchKernelGGL((attn_mfma<2>), dim3(2048), dim3(256), 0, stream, q, k, v, qT, kT, vT, ybuf, b);
    hipLaunchKernelGGL((repack<2>), dim3(512), dim3(256), 0, stream, ybuf, xblk, b);
  }
  hipLaunchKernelGGL(conv_mfma, dim3(2048), dim3(256), 0, stream,
                     xblk, wt2, cb, gamma, beta, mean, var, out);
}

// Round 8
// 368.925 us; speedup vs baseline: 3.7820x; 1.3240x over previous
//
#include <hip/hip_runtime.h>
#include <hip/hip_bf16.h>

// BS=2, C=32, S=64.
// ws: [0, 96 MiB)        xblk bf16 [b][ciq][64^3][32]   (blocked channels-last)
//     [96, 112 MiB)      y    bf16 [c][s][4096]          (single buffer, reused per branch)
//     [112,128,144 MiB)  qT,kT,vT f16 [c][d][w][h]       (per-b, reused)
//     [160 MiB, +166KB)  wt2  bf16 [tap][ciq][oct][co][8]
// out: (2,32,64,64,64) fp32.

#define CH 32

typedef __attribute__((ext_vector_type(8))) _Float16 f16x8;
typedef __attribute__((ext_vector_type(4))) _Float16 f16x4;
typedef __attribute__((ext_vector_type(8))) short bf16x8;
typedef __attribute__((ext_vector_type(4))) float f32x4;

static __device__ __forceinline__ unsigned short f2bf(float f) {
  union { float f; unsigned u; } x; x.f = f;
  unsigned r = x.u + 0x7fff + ((x.u >> 16) & 1);   // RNE
  return (unsigned short)(r >> 16);
}

// ---------------------------------------------------------------------------
// trans_dwh: q/k/v f32 [c][h][w][d] -> f16 [c][d][w][h] (one batch b).
// ---------------------------------------------------------------------------
__global__ __launch_bounds__(256) void trans_dwh(const float* __restrict__ q,
                                                 const float* __restrict__ k,
                                                 const float* __restrict__ v,
                                                 _Float16* __restrict__ qT,
                                                 _Float16* __restrict__ kT,
                                                 _Float16* __restrict__ vT,
                                                 int b) {
  __shared__ __align__(16) _Float16 Ls[64 * 72];
  const int blk = blockIdx.x;          // 2048 = c*64 + w
  const int c = blk >> 6;
  const int w = blk & 63;
  const int tid = threadIdx.x;
  const size_t bc = (size_t)(b * CH + c);
  const float* srcs[3] = {q, k, v};
  _Float16* dsts[3] = {qT, kT, vT};
  const int h = tid >> 2, dq = tid & 3;

  for (int tz = 0; tz < 3; ++tz) {
    const float* sp = srcs[tz] + bc * 262144 + (size_t)h * 4096 + (size_t)w * 64;
    #pragma unroll
    for (int pp = 0; pp < 4; ++pp) {
      const int d0 = dq * 16 + pp * 4;
      const float4 ld = *(const float4*)(sp + d0);
      Ls[(d0 + 0) * 72 + h] = (_Float16)ld.x;
      Ls[(d0 + 1) * 72 + h] = (_Float16)ld.y;
      Ls[(d0 + 2) * 72 + h] = (_Float16)ld.z;
      Ls[(d0 + 3) * 72 + h] = (_Float16)ld.w;
    }
    __syncthreads();
    _Float16* dp = dsts[tz] + (size_t)c * 262144 + (size_t)w * 64;
    #pragma unroll
    for (int p = 0; p < 2; ++p) {
      const int idx = p * 256 + tid;
      const int d = idx >> 3, o = (idx & 7) * 8;
      *(f16x8*)(dp + (size_t)d * 4096 + o) = *(const f16x8*)&Ls[d * 72 + o];
    }
    __syncthreads();
  }
}

// ---------------------------------------------------------------------------
// Axial attention via f16 MFMA (unchanged from round 7).
// ---------------------------------------------------------------------------
template <int BR>
__global__ __launch_bounds__(256) void attn_mfma(const float* __restrict__ q,
                                                 const float* __restrict__ k,
                                                 const float* __restrict__ v,
                                                 const _Float16* __restrict__ qT,
                                                 const _Float16* __restrict__ kT,
                                                 const _Float16* __restrict__ vT,
                                                 unsigned short* __restrict__ ybr,
                                                 int b) {
  __shared__ __align__(16) _Float16 Qh[64][72];
  __shared__ __align__(16) _Float16 Kh[64][72];
  __shared__ __align__(16) _Float16 Vh[64][72];

  const int blk0 = blockIdx.x;
  const int blk = ((blk0 & 7) << 8) | (blk0 >> 3);   // XCD chunk (2048 = 8*256)
  const int s = blk & 63;
  const int c = blk >> 6;
  const int tid = threadIdx.x;

  if (BR == 0) {
    const _Float16* qp = qT + ((size_t)c * 64 + s) * 4096;
    const _Float16* kp = kT + ((size_t)c * 64 + s) * 4096;
    const _Float16* vp = vT + ((size_t)c * 64 + s) * 4096;
    #pragma unroll
    for (int ii = 0; ii < 2; ++ii) {
      const int idx = ii * 256 + tid;
      const int row = idx >> 3, ch = (idx & 7) * 8;
      *(f16x8*)&Qh[row][ch] = *(const f16x8*)(qp + row * 64 + ch);
      *(f16x8*)&Kh[row][ch] = *(const f16x8*)(kp + row * 64 + ch);
      *(f16x8*)&Vh[row][ch] = *(const f16x8*)(vp + row * 64 + ch);   // Vt[t][j]
    }
  } else {
    const size_t base = ((size_t)(b * CH + c)) << 18;
    #pragma unroll
    for (int ii = 0; ii < 4; ++ii) {
      const int idx = ii * 256 + tid;
      const int hi = idx >> 4, lo = (idx & 15) * 4;
      size_t off;
      if (BR == 1) off = (size_t)hi * 4096 + (size_t)s * 64 + lo;
      else         off = (size_t)s * 4096 + (size_t)hi * 64 + lo;
      const float4 lq = *(const float4*)(q + base + off);
      const float4 lk = *(const float4*)(k + base + off);
      const float4 lv = *(const float4*)(v + base + off);
      *(f16x4*)&Qh[hi][lo] = (f16x4){(_Float16)lq.x, (_Float16)lq.y, (_Float16)lq.z, (_Float16)lq.w};
      *(f16x4*)&Kh[hi][lo] = (f16x4){(_Float16)lk.x, (_Float16)lk.y, (_Float16)lk.z, (_Float16)lk.w};
      *(f16x4*)&Vh[hi][lo] = (f16x4){(_Float16)lv.x, (_Float16)lv.y, (_Float16)lv.z, (_Float16)lv.w};
    }
  }
  __syncthreads();

  const int w = tid >> 6;
  const int lane = tid & 63;
  const int r = lane & 15;
  const int oct = lane >> 4;

  f32x4 sc[4];
  #pragma unroll
  for (int jt = 0; jt < 4; ++jt) sc[jt] = (f32x4){0.f, 0.f, 0.f, 0.f};
  f16x8 aq0 = *(const f16x8*)&Qh[w * 16 + r][oct * 8];
  f16x8 aq1 = *(const f16x8*)&Qh[w * 16 + r][32 + oct * 8];
  #pragma unroll
  for (int jt = 0; jt < 4; ++jt) {
    f16x8 bk0 = *(const f16x8*)&Kh[jt * 16 + r][oct * 8];
    f16x8 bk1 = *(const f16x8*)&Kh[jt * 16 + r][32 + oct * 8];
    sc[jt] = __builtin_amdgcn_mfma_f32_16x16x32_f16(aq0, bk0, sc[jt], 0, 0, 0);
    sc[jt] = __builtin_amdgcn_mfma_f32_16x16x32_f16(aq1, bk1, sc[jt], 0, 0, 0);
  }

  float P[4][4];
  #pragma unroll
  for (int reg = 0; reg < 4; ++reg) {
    float mx = fmaxf(fmaxf(sc[0][reg], sc[1][reg]), fmaxf(sc[2][reg], sc[3][reg]));
    mx = fmaxf(mx, __shfl_xor(mx, 1));
    mx = fmaxf(mx, __shfl_xor(mx, 2));
    mx = fmaxf(mx, __shfl_xor(mx, 4));
    mx = fmaxf(mx, __shfl_xor(mx, 8));
    float e[4], sum = 0.f;
    #pragma unroll
    for (int jt = 0; jt < 4; ++jt) { e[jt] = __expf(sc[jt][reg] - mx); sum += e[jt]; }
    sum += __shfl_xor(sum, 1);
    sum += __shfl_xor(sum, 2);
    sum += __shfl_xor(sum, 4);
    sum += __shfl_xor(sum, 8);
    const float inv = 1.f / sum;
    #pragma unroll
    for (int jt = 0; jt < 4; ++jt) P[reg][jt] = e[jt] * inv;
  }

  #pragma unroll
  for (int reg = 0; reg < 4; ++reg)
    #pragma unroll
    for (int jt = 0; jt < 4; ++jt)
      Qh[w * 16 + oct * 4 + reg][jt * 16 + r] = (_Float16)P[reg][jt];

  f16x8 ap0 = *(const f16x8*)&Qh[w * 16 + r][oct * 8];
  f16x8 ap1 = *(const f16x8*)&Qh[w * 16 + r][32 + oct * 8];
  f32x4 ot[4];
  #pragma unroll
  for (int tt = 0; tt < 4; ++tt) {
    ot[tt] = (f32x4){0.f, 0.f, 0.f, 0.f};
    f16x8 bv0, bv1;
    if (BR == 0) {
      bv0 = *(const f16x8*)&Vh[tt * 16 + r][oct * 8];
      bv1 = *(const f16x8*)&Vh[tt * 16 + r][32 + oct * 8];
    } else {
      #pragma unroll
      for (int e = 0; e < 8; ++e) {
        bv0[e] = Vh[oct * 8 + e][tt * 16 + r];
        bv1[e] = Vh[32 + oct * 8 + e][tt * 16 + r];
      }
    }
    ot[tt] = __builtin_amdgcn_mfma_f32_16x16x32_f16(ap0, bv0, ot[tt], 0, 0, 0);
    ot[tt] = __builtin_amdgcn_mfma_f32_16x16x32_f16(ap1, bv1, ot[tt], 0, 0, 0);
  }

  __syncthreads();
  unsigned short* Ot = (unsigned short*)&Kh[0][0];   // stride 72
  #pragma unroll
  for (int tt = 0; tt < 4; ++tt)
    #pragma unroll
    for (int reg = 0; reg < 4; ++reg)
      Ot[(size_t)(w * 16 + oct * 4 + reg) * 72 + tt * 16 + r] = f2bf(ot[tt][reg]);
  __syncthreads();

  {
    const int i = tid >> 2, seg = tid & 3;
    const unsigned short* src = Ot + (size_t)i * 72 + seg * 16;
    bf16x8 a0 = *(const bf16x8*)(src);
    bf16x8 a1 = *(const bf16x8*)(src + 8);
    unsigned short* dst = ybr + ((size_t)(c * 64 + s)) * 4096 + tid * 16;
    *(bf16x8*)(dst) = a0;
    *(bf16x8*)(dst + 8) = a1;
  }
}

// ---------------------------------------------------------------------------
// repack<BR>: y[c][s][i*64+t] -> xblk[(b*3+BR)][sp][32c], all coalesced.
// ---------------------------------------------------------------------------
template <int BR>
__global__ __launch_bounds__(256) void repack(const unsigned short* __restrict__ ybr,
                                              unsigned short* __restrict__ xblk,
                                              int b) {
  __shared__ unsigned short Ls[32 * 530];
  const int blk = blockIdx.x;        // 512
  const int oc = blk & 7;
  const int z = blk >> 3;
  const int tid = threadIdx.x;
  const int c = tid & 31;
  const int w8 = tid >> 5;           // 0..7

  size_t src;
  if (BR == 2) src = ((size_t)(c * 64 + z)) * 4096 + (size_t)(oc * 8 + w8) * 64;
  else         src = ((size_t)(c * 64 + oc * 8 + w8)) * 4096 + (size_t)z * 64;

  #pragma unroll
  for (int kk = 0; kk < 8; ++kk) {
    bf16x8 vv = *(const bf16x8*)(ybr + src + kk * 8);
    #pragma unroll
    for (int e = 0; e < 8; ++e) {
      const int l = kk * 8 + e;
      const int li = (BR == 0) ? (l * 8 + w8) : (w8 * 64 + l);
      Ls[c * 530 + li] = (unsigned short)vv[e];
    }
  }
  __syncthreads();

  unsigned short* xq = xblk + ((size_t)(b * 3 + BR)) * 262144 * 32;
  #pragma unroll
  for (int p = 0; p < 2; ++p) {
    const int o = p * 256 + tid;
    bf16x8 o0, o1, o2, o3;
    #pragma unroll
    for (int e = 0; e < 8; ++e) {
      o0[e] = (short)Ls[(e)      * 530 + o];
      o1[e] = (short)Ls[(8 + e)  * 530 + o];
      o2[e] = (short)Ls[(16 + e) * 530 + o];
      o3[e] = (short)Ls[(24 + e) * 530 + o];
    }
    int sp;
    if (BR == 0) sp = z * 4096 + (o >> 3) * 64 + oc * 8 + (o & 7);
    else         sp = z * 4096 + oc * 512 + o;
    unsigned short* dst = xq + (size_t)sp * 32;
    *(bf16x8*)(dst)      = o0;
    *(bf16x8*)(dst + 8)  = o1;
    *(bf16x8*)(dst + 16) = o2;
    *(bf16x8*)(dst + 24) = o3;
  }
}

// w[co][ci][dz][dy][dx] f32 -> wt2 bf16, idx = (((tap*3+ciq)*4+oct)*32 + co)*8 + e
__global__ __launch_bounds__(256) void wprep(const float* __restrict__ w,
                                             unsigned short* __restrict__ wt2) {
  int idx = blockIdx.x * 256 + threadIdx.x;
  if (idx >= 27 * 32 * 96) return;
  int tap = idx / 3072;
  int rem = idx - tap * 3072;
  int co = rem / 96, ci = rem - co * 96;
  int ciq = ci >> 5, oct = (ci >> 3) & 3, e = ci & 7;
  wt2[(((tap * 3 + ciq) * 4 + oct) * 32 + co) * 8 + e] =
      f2bf(w[((size_t)co * 96 + ci) * 27 + tap]);
}

// ---------------------------------------------------------------------------
// Z-PAIR LDS-staged implicit-GEMM conv. Block (4 waves) = (b, z-pair, 8-row
// y-tile). Outputs z0 and z0+1. Input planes z0-1..z0+2 staged ONCE per
// (plane, ciq); interior planes feed BOTH z-outputs -> each A-frag ds_read
// feeds 4 MFMAs (2 co-tiles x 2 z-outs). 12 stages vs 18 for same outputs.
// ---------------------------------------------------------------------------
__global__ __launch_bounds__(256, 2) void conv_mfma(const unsigned short* __restrict__ xblk,
                                                    const unsigned short* __restrict__ wt2,
                                                    const float* __restrict__ cb,
                                                    const float* __restrict__ gamma,
                                                    const float* __restrict__ beta,
                                                    const float* __restrict__ mean,
                                                    const float* __restrict__ var,
                                                    float* __restrict__ out) {
  __shared__ __align__(16) unsigned short XT[23760];   // 10*66*36 shorts

  const int blk0 = blockIdx.x;                       // 512
  const int blk = ((blk0 & 7) << 6) | (blk0 >> 3);   // XCD chunk (512 = 8*64)
  const int yt = blk & 7;
  const int zp = (blk >> 3) & 31;
  const int b = blk >> 8;
  const int tid = threadIdx.x;
  const int w = tid >> 6;
  const int lane = tid & 63;
  const int r = lane & 15;
  const int oct = lane >> 4;
  const int y0 = yt * 8;
  const int z0 = zp * 2;

  f32x4 acc0[2][4][2], acc1[2][4][2];
  #pragma unroll
  for (int ry = 0; ry < 2; ++ry)
    #pragma unroll
    for (int xc = 0; xc < 4; ++xc)
      #pragma unroll
      for (int ct = 0; ct < 2; ++ct) {
        acc0[ry][xc][ct] = (f32x4){0.f, 0.f, 0.f, 0.f};
        acc1[ry][xc][ct] = (f32x4){0.f, 0.f, 0.f, 0.f};
      }

  auto STAGE = [&](int p, int ciq) {
    const unsigned short* xq = xblk + ((size_t)(b * 3 + ciq)) * (262144ull * 32) +
                               (size_t)p * (4096 * 32);
    #pragma unroll
    for (int ii = 0; ii < 11; ++ii) {
      const int idx = ii * 256 + tid;
      if (idx < 2640) {
        const int row = idx / 264;
        const int rem = idx - row * 264;
        const int x = rem >> 2;
        const int cq = rem & 3;
        const int gy = y0 + row - 1, gx = x - 1;
        bf16x8 val = {0, 0, 0, 0, 0, 0, 0, 0};
        if ((unsigned)gy < 64u && (unsigned)gx < 64u)
          val = *(const bf16x8*)(xq + (size_t)(gy * 64 + gx) * 32 + cq * 8);
        *(bf16x8*)&XT[row * 2376 + x * 36 + cq * 8] = val;
      }
    }
  };

  // both z-outs valid: 4 MFMA per A-frag read
  auto C2 = [&](int dzA, int dzB, int ciq) {
    #pragma unroll
    for (int dy = 0; dy < 3; ++dy) {
      #pragma unroll
      for (int dx = 0; dx < 3; ++dx) {
        const unsigned short* wpA =
            wt2 + ((size_t)((((dzA * 3 + dy) * 3 + dx) * 3 + ciq) * 4 + oct)) * 256;
        const unsigned short* wpB =
            wt2 + ((size_t)((((dzB * 3 + dy) * 3 + dx) * 3 + ciq) * 4 + oct)) * 256;
        bf16x8 wA0 = *(const bf16x8*)(wpA + r * 8);
        bf16x8 wA1 = *(const bf16x8*)(wpA + 128 + r * 8);
        bf16x8 wB0 = *(const bf16x8*)(wpB + r * 8);
        bf16x8 wB1 = *(const bf16x8*)(wpB + 128 + r * 8);
        #pragma unroll
        for (int ry = 0; ry < 2; ++ry) {
          const int lrow = w * 2 + ry + dy;
          #pragma unroll
          for (int xc = 0; xc < 4; ++xc) {
            bf16x8 af = *(const bf16x8*)&XT[lrow * 2376 + (xc * 16 + r + dx) * 36 + oct * 8];
            acc0[ry][xc][0] = __builtin_amdgcn_mfma_f32_16x16x32_bf16(af, wA0, acc0[ry][xc][0], 0, 0, 0);
            acc0[ry][xc][1] = __builtin_amdgcn_mfma_f32_16x16x32_bf16(af, wA1, acc0[ry][xc][1], 0, 0, 0);
            acc1[ry][xc][0] = __builtin_amdgcn_mfma_f32_16x16x32_bf16(af, wB0, acc1[ry][xc][0], 0, 0, 0);
            acc1[ry][xc][1] = __builtin_amdgcn_mfma_f32_16x16x32_bf16(af, wB1, acc1[ry][xc][1], 0, 0, 0);
          }
        }
      }
    }
  };

  // single z-out valid (edge planes)
  auto C1 = [&](f32x4 (&A)[2][4][2], int dz, int ciq) {
    #pragma unroll
    for (int dy = 0; dy < 3; ++dy) {
      #pragma unroll
      for (int dx = 0; dx < 3; ++dx) {
        const unsigned short* wp =
            wt2 + ((size_t)((((dz * 3 + dy) * 3 + dx) * 3 + ciq) * 4 + oct)) * 256;
        bf16x8 w0 = *(const bf16x8*)(wp + r * 8);
        bf16x8 w1 = *(const bf16x8*)(wp + 128 + r * 8);
        #pragma unroll
        for (int ry = 0; ry < 2; ++ry) {
          const int lrow = w * 2 + ry + dy;
          #pragma unroll
          for (int xc = 0; xc < 4; ++xc) {
            bf16x8 af = *(const bf16x8*)&XT[lrow * 2376 + (xc * 16 + r + dx) * 36 + oct * 8];
            A[ry][xc][0] = __builtin_amdgcn_mfma_f32_16x16x32_bf16(af, w0, A[ry][xc][0], 0, 0, 0);
            A[ry][xc][1] = __builtin_amdgcn_mfma_f32_16x16x32_bf16(af, w1, A[ry][xc][1], 0, 0, 0);
          }
        }
      }
    }
  };

  #pragma unroll
  for (int ps = 0; ps < 4; ++ps) {
    const int p = z0 - 1 + ps;
    if ((unsigned)p > 63u) continue;   // uniform per block
    for (int ciq = 0; ciq < 3; ++ciq) {
      __syncthreads();
      STAGE(p, ciq);
      __syncthreads();
      if (ps == 0)      C1(acc0, 0, ciq);              // only z0, dz=0
      else if (ps == 3) C1(acc1, 2, ciq);              // only z0+1, dz=2
      else              C2(ps, ps - 1, ciq);           // both
    }
  }

  float invc[2], shc[2], bic[2];
  #pragma unroll
  for (int ct = 0; ct < 2; ++ct) {
    const int co = ct * 16 + r;
    const float iv = gamma[co] * rsqrtf(var[co] + 1e-5f);
    invc[ct] = iv;
    shc[ct] = beta[co] - mean[co] * iv;
    bic[ct] = cb[co];
  }

  auto STO = [&](f32x4 (&A)[2][4][2], int z) {
    #pragma unroll
    for (int ct = 0; ct < 2; ++ct) {
      float* oc = out + (((size_t)(b * CH + ct * 16 + r)) << 18) + ((size_t)z << 12);
      #pragma unroll
      for (int ry = 0; ry < 2; ++ry) {
        const int y = y0 + w * 2 + ry;
        #pragma unroll
        for (int xc = 0; xc < 4; ++xc) {
          const f32x4 a = A[ry][xc][ct];
          float4 st;
          st.x = fmaxf(0.f, (a[0] + bic[ct]) * invc[ct] + shc[ct]);
          st.y = fmaxf(0.f, (a[1] + bic[ct]) * invc[ct] + shc[ct]);
          st.z = fmaxf(0.f, (a[2] + bic[ct]) * invc[ct] + shc[ct]);
          st.w = fmaxf(0.f, (a[3] + bic[ct]) * invc[ct] + shc[ct]);
          *(float4*)(oc + (size_t)y * 64 + xc * 16 + oct * 4) = st;
        }
      }
    }
  };
  STO(acc0, z0);
  STO(acc1, z0 + 1);
}

extern "C" void kernel_launch(void* const* d_in, const int* in_sizes, int n_in,
                              void* d_out, int out_size, void* d_ws, size_t ws_size,
                              hipStream_t stream) {
  const float* q     = (const float*)d_in[0];
  const float* k     = (const float*)d_in[1];
  const float* v     = (const float*)d_in[2];
  const float* cw    = (const float*)d_in[3];
  const float* cb    = (const float*)d_in[4];
  const float* gamma = (const float*)d_in[5];
  const float* beta  = (const float*)d_in[6];
  const float* mean  = (const float*)d_in[7];
  const float* var   = (const float*)d_in[8];

  unsigned short* xblk = (unsigned short*)d_ws;                             // 96 MiB
  unsigned short* ybuf = (unsigned short*)((char*)d_ws + (96ull  << 20));   // 16 MiB
  _Float16*       qT   = (_Float16*)((char*)d_ws + (112ull << 20));         // 16 MiB
  _Float16*       kT   = (_Float16*)((char*)d_ws + (128ull << 20));         // 16 MiB
  _Float16*       vT   = (_Float16*)((char*)d_ws + (144ull << 20));         // 16 MiB
  unsigned short* wt2  = (unsigned short*)((char*)d_ws + (160ull << 20));   // 166 KB
  float* out = (float*)d_out;

  hipLaunchKernelGGL(wprep, dim3(324), dim3(256), 0, stream, cw, wt2);
  for (int b = 0; b < 2; ++b) {
    hipLaunchKernelGGL(trans_dwh, dim3(2048), dim3(256), 0, stream, q, k, v, qT, kT, vT, b);
    hipLaunchKernelGGL((attn_mfma<0>), dim3(2048), dim3(256), 0, stream, q, k, v, qT, kT, vT, ybuf, b);
    hipLaunchKernelGGL((repack<0>), dim3(512), dim3(256), 0, stream, ybuf, xblk, b);
    hipLaunchKernelGGL((attn_mfma<1>), dim3(2048), dim3(256), 0, stream, q, k, v, qT, kT, vT, ybuf, b);
    hipLaunchKernelGGL((repack<1>), dim3(512), dim3(256), 0, stream, ybuf, xblk, b);
    hipLaunchKernelGGL((attn_mfma<2>), dim3(2048), dim3(256), 0, stream, q, k, v, qT, kT, vT, ybuf, b);
    hipLaunchKernelGGL((repack<2>), dim3(512), dim3(256), 0, stream, ybuf, xblk, b);
  }
  hipLaunchKernelGGL(conv_mfma, dim3(512), dim3(256), 0, stream,
                     xblk, wt2, cb, gamma, beta, mean, var, out);
}